// Round 1
// baseline (837.483 us; speedup 1.0000x reference)
//
#include <hip/hip_runtime.h>
#include <cmath>

// SpikeFP32GELUExact: [B,S,32] {0,1} fp32 pulse bits -> decode IEEE-754 fp32
// -> exact fp64 tanh-GELU (reference op order) -> fp32 -> re-encode pulses.
//
// v2: one fp64 GELU per VALUE (was: 8x redundant, one per cooperating lane).
// A wave covers 64 consecutive values (512 float4s). Load phase: 8 coalesced
// 16B/lane iterations; each iteration decodes 8 values via nibble pack +
// width-8 shfl_xor OR-butterfly, then one extra shuffle transposes the
// assembled word to its owner lane (lane l owns value l of the wave's 64).
// Each lane runs the serial fp64 exp/div chain exactly once -> 8x less fp64
// issue + 8x fewer serial transcendental chains. Store phase mirrors the
// transpose. No LDS, no barriers; loads/stores stay fully coalesced.

__global__ __launch_bounds__(256) void spike_gelu_kernel(
    const float4* __restrict__ in, float4* __restrict__ out, long n4) {
  const unsigned l = threadIdx.x & 63u;                       // lane in wave
  const long wave_id = (((long)blockIdx.x * blockDim.x) + threadIdx.x) >> 6;
  const long fbase = wave_id * 512;                           // 512 float4s = 64 values
  if (fbase >= n4) return;                                    // wave-uniform guard

  const unsigned g = l & 7u;              // float4 position within a value (0..7)
  const unsigned s = 28u - 4u * g;        // nibble shift for that position
  const unsigned kown = l >> 3;           // load iteration that produces my value
  const unsigned src_in = (l & 7u) << 3;  // transpose-in source lane

  // ---- decode + transpose: after this loop, lane l holds value (wave*64+l)
  unsigned myu = 0u;
#pragma unroll
  for (unsigned k = 0; k < 8; ++k) {
    long fi = fbase + (long)(k * 64u + l);
    if (fi >= n4) fi = n4 - 1;            // safe clamp (sizes divide exactly)
    float4 p = in[fi];
    unsigned nib = ((p.x != 0.0f) ? 8u : 0u) | ((p.y != 0.0f) ? 4u : 0u) |
                   ((p.z != 0.0f) ? 2u : 0u) | ((p.w != 0.0f) ? 1u : 0u);
    unsigned u = nib << s;
    // OR-butterfly across the aligned 8-lane group: full 32-bit word in group
    u |= __shfl_xor(u, 1, 8);
    u |= __shfl_xor(u, 2, 8);
    u |= __shfl_xor(u, 4, 8);
    // route: value (k*8 + l&7)'s word lives in group (l&7) this iteration
    unsigned t = __shfl(u, (int)src_in, 64);
    if (kown == k) myu = t;
  }

  float xf = __uint_as_float(myu);

  // Exact mirror of the fp64 reference pipeline. Contraction OFF: the
  // reference rounds each mul/add separately; an fma here changes bits.
  double y;
  {
#pragma clang fp contract(off)
    double x = (double)xf;
    double x_cubed = (x * x) * x;
    double inner = x + 0.044715 * x_cubed;
    double two_z = 2.0 * (0.7978845608028654 * inner);
    double e = exp(two_z);
    double th = (e - 1.0) / (e + 1.0);
    y = 0.5 * (x * (1.0 + th));
  }
  unsigned r = __float_as_uint((float)y);

  // ---- transpose back + encode: iteration k stores float4s of values
  // vbase + k*8 .. vbase + k*8+7; lane l needs value k*8 + (l>>3)'s word,
  // owned by lane k*8 + (l>>3).
#pragma unroll
  for (unsigned k = 0; k < 8; ++k) {
    unsigned w = __shfl(r, (int)((k << 3) + kown), 64);
    float4 o;
    o.x = (float)((w >> (s + 3u)) & 1u);
    o.y = (float)((w >> (s + 2u)) & 1u);
    o.z = (float)((w >> (s + 1u)) & 1u);
    o.w = (float)((w >> s) & 1u);
    long fi = fbase + (long)(k * 64u + l);
    if (fi < n4) out[fi] = o;
  }
}

extern "C" void kernel_launch(void* const* d_in, const int* in_sizes, int n_in,
                              void* d_out, int out_size, void* d_ws, size_t ws_size,
                              hipStream_t stream) {
  const float4* in = (const float4*)d_in[0];
  float4* out = (float4*)d_out;
  long n4 = (long)in_sizes[0] / 4;        // 33,554,432 float4s
  long nvals = n4 / 8;                    // 4,194,304 fp32 values
  int block = 256;
  long grid = (nvals + block - 1) / block;
  spike_gelu_kernel<<<(int)grid, block, 0, stream>>>(in, out, n4);
}

// Round 2
// 822.943 us; speedup vs baseline: 1.0177x; 1.0177x over previous
//
#include <hip/hip_runtime.h>
#include <cmath>

// SpikeFP32GELUExact: [B,S,32] {0,1} fp32 pulse bits -> decode IEEE-754 fp32
// -> exact fp64 tanh-GELU (reference op order) -> fp32 -> re-encode pulses.
//
// v3: v1 structure (8 lanes cooperate per value via width-8 shfl_xor
// OR-butterfly; redundant fp64 per lane — proven NOT the bottleneck by v2's
// null result), plus:
//  - nontemporal loads/stores: both streams are touch-once; nt hints stop
//    the 537MB read + 537MB write streams from thrashing L2/L3 allocation.
//  - 4 float4s per thread (grid-stride, stride multiple of 8 so the
//    lane&7 <-> nibble-position mapping is preserved): 4 independent 16B
//    loads in flight per thread before compute (more MLP per wave-slot).
// Memory-bound: 1.074 GB total traffic, floor ~170 us at 6.3 TB/s.

typedef float f4v __attribute__((ext_vector_type(4)));

__global__ __launch_bounds__(256) void spike_gelu_kernel(
    const f4v* __restrict__ in, f4v* __restrict__ out, long n4) {
  const long nthreads = (long)gridDim.x * (long)blockDim.x;
  const long f0 = (long)blockIdx.x * (long)blockDim.x + (long)threadIdx.x;
  const unsigned g = (unsigned)threadIdx.x & 7u;  // float4 pos in value (0..7)
  const unsigned s = 28u - 4u * g;                // nibble shift

  // Issue all 4 loads up front (independent -> 4 in flight).
  long f[4];
  f4v p[4];
#pragma unroll
  for (int i = 0; i < 4; ++i) {
    long fi = f0 + (long)i * nthreads;
    if (fi >= n4) fi = n4 - 1;  // clamp (sizes divide exactly in practice)
    f[i] = fi;
    p[i] = __builtin_nontemporal_load(&in[fi]);
  }

#pragma unroll
  for (int i = 0; i < 4; ++i) {
    // Pack 4 pulses into a nibble, place at this lane's position.
    unsigned nib = ((p[i][0] != 0.0f) ? 8u : 0u) | ((p[i][1] != 0.0f) ? 4u : 0u) |
                   ((p[i][2] != 0.0f) ? 2u : 0u) | ((p[i][3] != 0.0f) ? 1u : 0u);
    unsigned u = nib << s;
    // OR-butterfly across the aligned 8-lane group: full word in every lane.
    u |= __shfl_xor(u, 1, 8);
    u |= __shfl_xor(u, 2, 8);
    u |= __shfl_xor(u, 4, 8);
    float xf = __uint_as_float(u);

    // Exact mirror of the fp64 reference pipeline. Contraction OFF: the
    // reference rounds each mul/add separately; an fma here changes bits.
    double y;
    {
#pragma clang fp contract(off)
      double x = (double)xf;
      double x_cubed = (x * x) * x;
      double inner = x + 0.044715 * x_cubed;
      double two_z = 2.0 * (0.7978845608028654 * inner);
      double e = exp(two_z);
      double th = (e - 1.0) / (e + 1.0);
      y = 0.5 * (x * (1.0 + th));
    }
    unsigned r = __float_as_uint((float)y);

    // Re-encode: this lane writes pulses 4g..4g+3 = bits (31-4g)..(28-4g).
    f4v o;
    o[0] = (float)((r >> (s + 3u)) & 1u);
    o[1] = (float)((r >> (s + 2u)) & 1u);
    o[2] = (float)((r >> (s + 1u)) & 1u);
    o[3] = (float)((r >> s) & 1u);
    __builtin_nontemporal_store(o, &out[f[i]]);
  }
}

extern "C" void kernel_launch(void* const* d_in, const int* in_sizes, int n_in,
                              void* d_out, int out_size, void* d_ws, size_t ws_size,
                              hipStream_t stream) {
  const f4v* in = (const f4v*)d_in[0];
  f4v* out = (f4v*)d_out;
  long n4 = (long)in_sizes[0] / 4;  // 33,554,432 float4s
  const int block = 256;
  const int per_thread = 4;
  long grid = (n4 + (long)block * per_thread - 1) / ((long)block * per_thread);
  spike_gelu_kernel<<<(int)grid, block, 0, stream>>>(in, out, n4);
}